// Round 7
// baseline (3555.782 us; speedup 1.0000x reference)
//
#include <hip/hip_runtime.h>

// Causal MHA. B=4, S=2048, V=1024, H=16, hs=64.
// R7: identical math to R6; OUTPUT NOW WRITTEN AS FP32 (reference returns
// fp32; prior rounds wrote packed bf16 -> harness read fp32 -> absmax 4.609
// invariant across all internal changes).
#define B_  4
#define S_  2048
#define V_  1024
#define H_  16
#define HS_ 64
#define M_  (B_*S_)   // 8192 tokens
#define GK_ 1024
#define GN_ 1024

typedef unsigned short u16;

__device__ __forceinline__ float bf2f(u16 u) {
  return __uint_as_float(((unsigned int)u) << 16);
}
__device__ __forceinline__ float lo16(unsigned int w) { return __uint_as_float(w << 16); }
__device__ __forceinline__ float hi16(unsigned int w) { return __uint_as_float(w & 0xffff0000u); }
__device__ __forceinline__ u16 f2bf(float f) {
  unsigned int u = __float_as_uint(f);
  unsigned int r = u + 0x7fffu + ((u >> 16) & 1u);  // RNE
  return (u16)(r >> 16);
}

// ---------------------------------------------------------------------------
// Input-storage detector over 16384 words of x.
// isf32 = (count(lo16==0) > 8192) || (count(bf16-NaN pattern) > 0).
// Handles: full fp32, bf16-rounded fp32 (low mantissa zero), packed bf16.
// ---------------------------------------------------------------------------
__global__ __launch_bounds__(256) void detect_kernel(
    const unsigned int* __restrict__ x32, int* __restrict__ flag)
{
  __shared__ int zred[256];
  __shared__ int nred[256];
  const int tid = threadIdx.x;
  int nz = 0, nn = 0;
  for (int i = tid; i < 16384; i += 256) {
    unsigned int lo = x32[i] & 0xffffu;
    if (lo == 0u) nz++;
    if ((lo & 0x7f80u) == 0x7f80u && (lo & 0x7fu) != 0u) nn++;  // bf16 NaN
  }
  zred[tid] = nz; nred[tid] = nn;
  __syncthreads();
  for (int s = 128; s > 0; s >>= 1) {
    if (tid < s) { zred[tid] += zred[tid + s]; nred[tid] += nred[tid + s]; }
    __syncthreads();
  }
  if (tid == 0) *flag = (zred[0] > 8192 || nred[0] > 0) ? 1 : 0;
}

// ---------------------------------------------------------------------------
// QKV projection for ONE batch b. One thread per (s,h) token-head.
// q,k,v per-batch layout [h][s][d] (d contiguous), bf16.
// ---------------------------------------------------------------------------
__global__ __launch_bounds__(256) void qkv_kernel(
    const void* __restrict__ x, int b, const void* __restrict__ w,
    u16* __restrict__ q, u16* __restrict__ k, u16* __restrict__ v,
    const int* __restrict__ flag)
{
  __shared__ __align__(16) float Ws[192 * 64];   // 48 KB
  const int tid = threadIdx.x;
  const int isf32 = *flag;
  if (isf32) {
    for (int i = tid; i < 192 * 64; i += 256) Ws[i] = ((const float*)w)[i];
  } else {
    for (int i = tid; i < 192 * 64; i += 256) Ws[i] = bf2f(((const u16*)w)[i]);
  }
  __syncthreads();

  const int th = blockIdx.x * 256 + tid;     // [0, 32768): h fastest
  const int h = th & (H_ - 1);
  const int s = th >> 4;                     // [0, 2048)
  const size_t xoff = ((size_t)b * S_ + s) * V_ + h * HS_;

  float xf[64];
  if (isf32) {
    const float4* xp = (const float4*)((const float*)x + xoff);
#pragma unroll
    for (int i = 0; i < 16; ++i) {
      float4 u = xp[i];
      xf[4*i+0] = u.x; xf[4*i+1] = u.y; xf[4*i+2] = u.z; xf[4*i+3] = u.w;
    }
  } else {
    const uint4* xp = (const uint4*)((const u16*)x + xoff);
#pragma unroll
    for (int i = 0; i < 8; ++i) {
      uint4 u = xp[i];
      xf[8*i+0] = lo16(u.x); xf[8*i+1] = hi16(u.x);
      xf[8*i+2] = lo16(u.y); xf[8*i+3] = hi16(u.y);
      xf[8*i+4] = lo16(u.z); xf[8*i+5] = hi16(u.z);
      xf[8*i+6] = lo16(u.w); xf[8*i+7] = hi16(u.w);
    }
  }

  const size_t obase = ((size_t)h * S_ + s) * HS_;
#pragma unroll 1
  for (int eg = 0; eg < 12; ++eg) {          // 16 outputs each; 0-3:q 4-7:k 8-11:v
    float acc[16];
#pragma unroll
    for (int ee = 0; ee < 16; ++ee) {
      const float4* wr = (const float4*)&Ws[(eg * 16 + ee) * 64];
      float a = 0.f;
#pragma unroll
      for (int d4 = 0; d4 < 16; ++d4) {
        float4 wv = wr[d4];
        a += xf[d4*4+0]*wv.x + xf[d4*4+1]*wv.y + xf[d4*4+2]*wv.z + xf[d4*4+3]*wv.w;
      }
      acc[ee] = a;
    }
    u16* dst = (eg < 4) ? q : (eg < 8) ? k : v;
    const int d0 = (eg & 3) * 16;
    unsigned int p[8];
#pragma unroll
    for (int t = 0; t < 8; ++t)
      p[t] = (unsigned int)f2bf(acc[2*t]) | ((unsigned int)f2bf(acc[2*t+1]) << 16);
    uint4* dp = (uint4*)(dst + obase + d0);
    dp[0] = make_uint4(p[0], p[1], p[2], p[3]);
    dp[1] = make_uint4(p[4], p[5], p[6], p[7]);
  }
}

// ---------------------------------------------------------------------------
// Causal flash attention for ONE batch (vector). Block per (h, query row i).
// q,k,v: per-batch [h][s][d]. o: per-batch [s][V] with o[s][h*64+d], bf16.
// ---------------------------------------------------------------------------
__global__ __launch_bounds__(256) void attn_kernel(
    const u16* __restrict__ q, const u16* __restrict__ k,
    const u16* __restrict__ v, u16* __restrict__ o)
{
  const int i   = blockIdx.x;
  const int h   = blockIdx.y;
  const int tid = threadIdx.x;
  __shared__ __align__(16) float qs[64];
  __shared__ float ps[256];
  __shared__ float red[8];
  __shared__ __align__(16) float opart[16][64];

  const u16* qrow = q + ((size_t)h * S_ + i) * HS_;
  if (tid < 64) qs[tid] = bf2f(qrow[tid]) * 0.125f;   // scale = 1/sqrt(64)
  __syncthreads();

  const int lane = tid & 63;
  const int wid  = tid >> 6;
  const int jg   = tid >> 4;
  const int dq   = tid & 15;

  float m_run = -INFINITY, l_run = 0.f;
  float oa0 = 0.f, oa1 = 0.f, oa2 = 0.f, oa3 = 0.f;

  const int nch = (i >> 8) + 1;
  for (int c = 0; c < nch; ++c) {
    const int j = (c << 8) + tid;
    float sv = -INFINITY;
    if (j <= i) {
      const uint4* kr = (const uint4*)(k + ((size_t)h * S_ + j) * HS_);
      float a = 0.f;
#pragma unroll
      for (int t = 0; t < 8; ++t) {
        uint4 u = kr[t];
        float4 q0 = *(const float4*)&qs[t * 8];
        float4 q1 = *(const float4*)&qs[t * 8 + 4];
        a += lo16(u.x)*q0.x + hi16(u.x)*q0.y + lo16(u.y)*q0.z + hi16(u.y)*q0.w
           + lo16(u.z)*q1.x + hi16(u.z)*q1.y + lo16(u.w)*q1.z + hi16(u.w)*q1.w;
      }
      sv = a;
    }
    float mx = sv;
#pragma unroll
    for (int off = 32; off > 0; off >>= 1) mx = fmaxf(mx, __shfl_xor(mx, off));
    if (lane == 0) red[wid] = mx;
    __syncthreads();
    const float cmax  = fmaxf(fmaxf(red[0], red[1]), fmaxf(red[2], red[3]));
    const float m_new = fmaxf(m_run, cmax);
    const float p = __expf(sv - m_new);       // masked -> 0
    ps[tid] = p;
    float sm = p;
#pragma unroll
    for (int off = 32; off > 0; off >>= 1) sm += __shfl_xor(sm, off);
    if (lane == 0) red[4 + wid] = sm;
    __syncthreads();                          // ps + red[4..7] visible
    const float csum  = red[4] + red[5] + red[6] + red[7];
    const float alpha = __expf(m_run - m_new);
    m_run = m_new;
    l_run = l_run * alpha + csum;
    oa0 *= alpha; oa1 *= alpha; oa2 *= alpha; oa3 *= alpha;

    const int jbase = (c << 8) + jg * 16;
    if (jbase <= i) {
      const u16* vb = v + ((size_t)h * S_ + jbase) * HS_ + dq * 4;
      const float* pp = &ps[jg * 16];
#pragma unroll
      for (int t = 0; t < 16; ++t) {
        const float pv = pp[t];
        uint2 u = *(const uint2*)(vb + (size_t)t * HS_);
        oa0 += pv * lo16(u.x); oa1 += pv * hi16(u.x);
        oa2 += pv * lo16(u.y); oa3 += pv * hi16(u.y);
      }
    }
    __syncthreads();                          // protect ps/red
  }

  opart[jg][dq*4+0] = oa0; opart[jg][dq*4+1] = oa1;
  opart[jg][dq*4+2] = oa2; opart[jg][dq*4+3] = oa3;
  __syncthreads();
  if (tid < 64) {
    float r = 0.f;
#pragma unroll
    for (int g = 0; g < 16; ++g) r += opart[g][tid];
    o[(size_t)i * V_ + h * HS_ + tid] = f2bf(r / l_run);
  }
}

// ---------------------------------------------------------------------------
// Output projection for ONE batch, VECTOR NT-GEMM, FP32 OUTPUT.
// outb[m][n] = sum_k o[m][k] * W_out[n][k]. 64x64 tile, 4x4 per thread.
// LDS tiles transposed ([k][m], [k][n], stride 68): conflict-free float4.
// ---------------------------------------------------------------------------
__global__ __launch_bounds__(256) void oproj_vec_kernel(
    const u16* __restrict__ o, const void* __restrict__ w,
    float* __restrict__ outb, const int* __restrict__ flag)
{
  __shared__ __align__(16) float At[64 * 68];   // [k][m]
  __shared__ __align__(16) float Wt[64 * 68];   // [k][n]
  const int tid = threadIdx.x;
  const int m0 = blockIdx.x * 64;               // local row within batch
  const int n0 = blockIdx.y * 64;
  const int tr = tid >> 4;
  const int tc = tid & 15;
  const int isf32 = *flag;

  const int srow = tid >> 2;          // 0..63
  const int sc   = (tid & 3) * 16;    // k-chunk 0,16,32,48

  float acc[4][4] = {};

  for (int k0 = 0; k0 < GK_; k0 += 64) {
    float av[16], wv[16];
    {
      const u16* gp = o + (size_t)(m0 + srow) * GK_ + k0 + sc;
      uint4 u0 = *(const uint4*)gp;
      uint4 u1 = *(const uint4*)(gp + 8);
      av[0]=lo16(u0.x); av[1]=hi16(u0.x); av[2]=lo16(u0.y); av[3]=hi16(u0.y);
      av[4]=lo16(u0.z); av[5]=hi16(u0.z); av[6]=lo16(u0.w); av[7]=hi16(u0.w);
      av[8]=lo16(u1.x); av[9]=hi16(u1.x); av[10]=lo16(u1.y); av[11]=hi16(u1.y);
      av[12]=lo16(u1.z); av[13]=hi16(u1.z); av[14]=lo16(u1.w); av[15]=hi16(u1.w);
    }
    if (isf32) {
      const float4* gp = (const float4*)((const float*)w + (size_t)(n0 + srow) * GK_ + k0 + sc);
#pragma unroll
      for (int i = 0; i < 4; ++i) {
        float4 f = gp[i];
        wv[4*i+0]=f.x; wv[4*i+1]=f.y; wv[4*i+2]=f.z; wv[4*i+3]=f.w;
      }
    } else {
      const u16* gp = (const u16*)w + (size_t)(n0 + srow) * GK_ + k0 + sc;
      uint4 u0 = *(const uint4*)gp;
      uint4 u1 = *(const uint4*)(gp + 8);
      wv[0]=lo16(u0.x); wv[1]=hi16(u0.x); wv[2]=lo16(u0.y); wv[3]=hi16(u0.y);
      wv[4]=lo16(u0.z); wv[5]=hi16(u0.z); wv[6]=lo16(u0.w); wv[7]=hi16(u0.w);
      wv[8]=lo16(u1.x); wv[9]=hi16(u1.x); wv[10]=lo16(u1.y); wv[11]=hi16(u1.y);
      wv[12]=lo16(u1.z); wv[13]=hi16(u1.z); wv[14]=lo16(u1.w); wv[15]=hi16(u1.w);
    }
    __syncthreads();                  // prior inner-loop reads done
#pragma unroll
    for (int i = 0; i < 16; ++i) {    // transposed store: [k][row]
      At[(sc + i) * 68 + srow] = av[i];
      Wt[(sc + i) * 68 + srow] = wv[i];
    }
    __syncthreads();                  // tile ready

#pragma unroll 4
    for (int kk = 0; kk < 64; ++kk) {
      float4 a4 = *(const float4*)&At[kk * 68 + tr * 4];
      float4 w4 = *(const float4*)&Wt[kk * 68 + tc * 4];
      acc[0][0] += a4.x*w4.x; acc[0][1] += a4.x*w4.y; acc[0][2] += a4.x*w4.z; acc[0][3] += a4.x*w4.w;
      acc[1][0] += a4.y*w4.x; acc[1][1] += a4.y*w4.y; acc[1][2] += a4.y*w4.z; acc[1][3] += a4.y*w4.w;
      acc[2][0] += a4.z*w4.x; acc[2][1] += a4.z*w4.y; acc[2][2] += a4.z*w4.z; acc[2][3] += a4.z*w4.w;
      acc[3][0] += a4.w*w4.x; acc[3][1] += a4.w*w4.y; acc[3][2] += a4.w*w4.z; acc[3][3] += a4.w*w4.w;
    }
  }

#pragma unroll
  for (int r = 0; r < 4; ++r) {
    const int row = m0 + tr * 4 + r;
    *(float4*)(outb + (size_t)row * GN_ + n0 + tc * 4) =
        make_float4(acc[r][0], acc[r][1], acc[r][2], acc[r][3]);
  }
}

// ---------------------------------------------------------------------------
extern "C" void kernel_launch(void* const* d_in, const int* in_sizes, int n_in,
                              void* d_out, int out_size, void* d_ws, size_t ws_size,
                              hipStream_t stream) {
  // Defensive input identification by element count (no-op if dict order holds)
  const void* x = d_in[0];
  const void* wqkv = (n_in > 1) ? d_in[1] : d_in[0];
  const void* wout = (n_in > 2) ? d_in[2] : d_in[0];
  for (int i = 0; i < n_in; ++i) {
    if      (in_sizes[i] == B_ * S_ * V_) x    = d_in[i];   // 8388608
    else if (in_sizes[i] == 3 * HS_ * HS_) wqkv = d_in[i];  // 12288
    else if (in_sizes[i] == V_ * V_)      wout = d_in[i];   // 1048576
  }
  float* out = (float*)d_out;   // [B,S,V] fp32 (reference output dtype)

  const size_t per_b = (size_t)H_ * S_ * HS_;   // 2,097,152 elems = 4 MiB bf16
  int* flag = (int*)d_ws;
  u16* q = (u16*)((char*)d_ws + 16);
  u16* k = q + per_b;
  u16* v = k + per_b;
  u16* o = v + per_b;                           // [S, V] per batch (4 MiB)
  // total ws use: 16 B + 16 MiB

  detect_kernel<<<dim3(1), dim3(256), 0, stream>>>((const unsigned int*)x, flag);
  for (int b = 0; b < B_; ++b) {
    qkv_kernel<<<dim3((S_ * H_) / 256), dim3(256), 0, stream>>>(x, b, wqkv, q, k, v, flag);
    attn_kernel<<<dim3(S_, H_), dim3(256), 0, stream>>>(q, k, v, o);
    oproj_vec_kernel<<<dim3(S_ / 64, GN_ / 64), dim3(256), 0, stream>>>(
        o, wout, out + (size_t)b * S_ * V_, flag);
  }
}

// Round 8
// 551.396 us; speedup vs baseline: 6.4487x; 6.4487x over previous
//
#include <hip/hip_runtime.h>

// Causal MHA. B=4, S=2048, V=1024, H=16, hs=64. Inputs via runtime dtype
// detect; output fp32. R8: MFMA flash attention (16x16x32 bf16) replaces the
// vector attn (was 89% of runtime, MfmaUtil=0). oproj stays vector (isolation).
#define B_  4
#define S_  2048
#define V_  1024
#define H_  16
#define HS_ 64
#define GK_ 1024
#define GN_ 1024

typedef unsigned short u16;
typedef __bf16 bf16x8 __attribute__((ext_vector_type(8)));
typedef float  f32x4  __attribute__((ext_vector_type(4)));

__device__ __forceinline__ float bf2f(u16 u) {
  return __uint_as_float(((unsigned int)u) << 16);
}
__device__ __forceinline__ float lo16(unsigned int w) { return __uint_as_float(w << 16); }
__device__ __forceinline__ float hi16(unsigned int w) { return __uint_as_float(w & 0xffff0000u); }
__device__ __forceinline__ u16 f2bf(float f) {
  unsigned int u = __float_as_uint(f);
  unsigned int r = u + 0x7fffu + ((u >> 16) & 1u);  // RNE
  return (u16)(r >> 16);
}

// ---------------------------------------------------------------------------
// Input-storage detector (see R5/R7 notes). isf32 = low-halves mostly zero
// (bf16-rounded fp32) or any bf16-NaN bit pattern (random fp32 mantissa).
// ---------------------------------------------------------------------------
__global__ __launch_bounds__(256) void detect_kernel(
    const unsigned int* __restrict__ x32, int* __restrict__ flag)
{
  __shared__ int zred[256];
  __shared__ int nred[256];
  const int tid = threadIdx.x;
  int nz = 0, nn = 0;
  for (int i = tid; i < 16384; i += 256) {
    unsigned int lo = x32[i] & 0xffffu;
    if (lo == 0u) nz++;
    if ((lo & 0x7f80u) == 0x7f80u && (lo & 0x7fu) != 0u) nn++;
  }
  zred[tid] = nz; nred[tid] = nn;
  __syncthreads();
  for (int s = 128; s > 0; s >>= 1) {
    if (tid < s) { zred[tid] += zred[tid + s]; nred[tid] += nred[tid + s]; }
    __syncthreads();
  }
  if (tid == 0) *flag = (zred[0] > 8192 || nred[0] > 0) ? 1 : 0;
}

// ---------------------------------------------------------------------------
// QKV projection, batch = b0 + blockIdx.z. q,k,v: [z][h][s][d] bf16.
// ---------------------------------------------------------------------------
__global__ __launch_bounds__(256) void qkv_kernel(
    const void* __restrict__ x, int b0, const void* __restrict__ w,
    u16* __restrict__ q, u16* __restrict__ k, u16* __restrict__ v,
    const int* __restrict__ flag)
{
  __shared__ __align__(16) float Ws[192 * 64];   // 48 KB
  const int tid = threadIdx.x;
  const int isf32 = *flag;
  if (isf32) {
    for (int i = tid; i < 192 * 64; i += 256) Ws[i] = ((const float*)w)[i];
  } else {
    for (int i = tid; i < 192 * 64; i += 256) Ws[i] = bf2f(((const u16*)w)[i]);
  }
  __syncthreads();

  const int th = blockIdx.x * 256 + tid;     // [0, 32768): h fastest
  const int h = th & (H_ - 1);
  const int s = th >> 4;
  const int b = b0 + blockIdx.z;
  const size_t zoff = (size_t)blockIdx.z * H_ * S_ * HS_;
  const size_t xoff = ((size_t)b * S_ + s) * V_ + h * HS_;

  float xf[64];
  if (isf32) {
    const float4* xp = (const float4*)((const float*)x + xoff);
#pragma unroll
    for (int i = 0; i < 16; ++i) {
      float4 u = xp[i];
      xf[4*i+0] = u.x; xf[4*i+1] = u.y; xf[4*i+2] = u.z; xf[4*i+3] = u.w;
    }
  } else {
    const uint4* xp = (const uint4*)((const u16*)x + xoff);
#pragma unroll
    for (int i = 0; i < 8; ++i) {
      uint4 u = xp[i];
      xf[8*i+0] = lo16(u.x); xf[8*i+1] = hi16(u.x);
      xf[8*i+2] = lo16(u.y); xf[8*i+3] = hi16(u.y);
      xf[8*i+4] = lo16(u.z); xf[8*i+5] = hi16(u.z);
      xf[8*i+6] = lo16(u.w); xf[8*i+7] = hi16(u.w);
    }
  }

  const size_t obase = zoff + ((size_t)h * S_ + s) * HS_;
#pragma unroll 1
  for (int eg = 0; eg < 12; ++eg) {
    float acc[16];
#pragma unroll
    for (int ee = 0; ee < 16; ++ee) {
      const float4* wr = (const float4*)&Ws[(eg * 16 + ee) * 64];
      float a = 0.f;
#pragma unroll
      for (int d4 = 0; d4 < 16; ++d4) {
        float4 wv = wr[d4];
        a += xf[d4*4+0]*wv.x + xf[d4*4+1]*wv.y + xf[d4*4+2]*wv.z + xf[d4*4+3]*wv.w;
      }
      acc[ee] = a;
    }
    u16* dst = (eg < 4) ? q : (eg < 8) ? k : v;
    const int d0 = (eg & 3) * 16;
    unsigned int p[8];
#pragma unroll
    for (int t = 0; t < 8; ++t)
      p[t] = (unsigned int)f2bf(acc[2*t]) | ((unsigned int)f2bf(acc[2*t+1]) << 16);
    uint4* dp = (uint4*)(dst + obase + d0);
    dp[0] = make_uint4(p[0], p[1], p[2], p[3]);
    dp[1] = make_uint4(p[4], p[5], p[6], p[7]);
  }
}

// ---------------------------------------------------------------------------
// MFMA flash attention. Block = 4 waves = 64 Q rows of one (z, head).
// q,k,v: [z][h][s][64] bf16. o: [z][s][V] bf16 (o[s][h*64+d]).
// mfma_f32_16x16x32_bf16: A/B frag row|col=lane&15, k=(lane>>4)*8+j;
// C/D: col=lane&15, row=(lane>>4)*4+reg  [m89/m91 verified].
// K tile LDS [j][d] stride 72; V tile TRANSPOSED [d][j] stride 72 so PV
// B-frags are contiguous b128. P round-trips through per-wave LDS (m120).
// Swizzle: qq=(qblk+8z)&31, h&8 -> 31-qq: heavy/light pairing per CU.
// ---------------------------------------------------------------------------
__global__ __launch_bounds__(256) void attn_mfma_kernel(
    const u16* __restrict__ q, const u16* __restrict__ k,
    const u16* __restrict__ v, u16* __restrict__ o)
{
  const int z   = blockIdx.z;
  const int h   = blockIdx.y;
  int qq = (blockIdx.x + 8 * z) & 31;
  if (h & 8) qq = 31 - qq;
  const int qb  = qq * 64;
  const int tid = threadIdx.x;
  const int w = tid >> 6, lane = tid & 63;
  const int col = lane & 15, quad = lane >> 4;

  __shared__ __align__(16) u16 Ks[64 * 72];      // 9216 B
  __shared__ __align__(16) u16 Vt[64 * 72];      // 9216 B
  __shared__ __align__(16) u16 Ps[4][16 * 72];   // 9216 B

  const size_t zq = (size_t)z * H_ * S_ * HS_;
  const size_t hs = zq + (size_t)h * S_ * HS_;

  // Q fragments, prescaled by 1/8 (exact in bf16)
  bf16x8 qf[2];
  {
    const u16* qp = q + hs + (size_t)(qb + w * 16 + col) * HS_ + quad * 8;
#pragma unroll
    for (int ks = 0; ks < 2; ++ks) {
      u16 t8[8];
      *(uint4*)t8 = *(const uint4*)(qp + ks * 32);
#pragma unroll
      for (int e = 0; e < 8; ++e) t8[e] = f2bf(bf2f(t8[e]) * 0.125f);
      qf[ks] = *(bf16x8*)t8;
    }
  }

  const int sr = tid >> 2, sc = (tid & 3) * 16;   // K staging
  const int vrow = tid & 63, vc = (tid >> 6) * 16; // V staging (transpose)
  const int irow = qb + w * 16 + quad * 4;         // this lane's acc rows base

  f32x4 oacc[4] = {};
  float m_run[4] = {-INFINITY, -INFINITY, -INFINITY, -INFINITY};
  float l_run[4] = {0.f, 0.f, 0.f, 0.f};

  for (int jb = 0; jb <= qb; jb += 64) {
    // prefetch tiles to regs
    const u16* kp = k + hs + (size_t)(jb + sr) * HS_ + sc;
    uint4 k0 = *(const uint4*)kp;
    uint4 k1 = *(const uint4*)(kp + 8);
    const u16* vp = v + hs + (size_t)(jb + vrow) * HS_ + vc;
    uint4 v0 = *(const uint4*)vp;
    uint4 v1 = *(const uint4*)(vp + 8);
    __syncthreads();                     // prior tile reads done
    *(uint4*)(Ks + sr * 72 + sc)     = k0;
    *(uint4*)(Ks + sr * 72 + sc + 8) = k1;
    {
      u16 t16[16];
      *(uint4*)t16 = v0; *(uint4*)(t16 + 8) = v1;
#pragma unroll
      for (int e = 0; e < 16; ++e) Vt[(vc + e) * 72 + vrow] = t16[e];
    }
    __syncthreads();                     // tile visible

    // QK^T: S[i][j], i=16 rows of this wave, j=64
    f32x4 sacc[4] = {};
#pragma unroll
    for (int ks = 0; ks < 2; ++ks)
#pragma unroll
      for (int t = 0; t < 4; ++t) {
        const bf16x8 kf = *(const bf16x8*)(Ks + (t * 16 + col) * 72 + ks * 32 + quad * 8);
        sacc[t] = __builtin_amdgcn_mfma_f32_16x16x32_bf16(qf[ks], kf, sacc[t], 0, 0, 0);
      }

    float s[4][4];
#pragma unroll
    for (int t = 0; t < 4; ++t)
#pragma unroll
      for (int r = 0; r < 4; ++r) s[t][r] = sacc[t][r];

    if (jb == qb) {                      // diagonal tile: mask j > i
#pragma unroll
      for (int t = 0; t < 4; ++t) {
        const int j = jb + t * 16 + col;
#pragma unroll
        for (int r = 0; r < 4; ++r)
          if (j > irow + r) s[t][r] = -INFINITY;
      }
    }

    // online softmax: row stats via 16-lane butterfly within quads
    float mrow[4];
#pragma unroll
    for (int r = 0; r < 4; ++r)
      mrow[r] = fmaxf(fmaxf(s[0][r], s[1][r]), fmaxf(s[2][r], s[3][r]));
#pragma unroll
    for (int off = 1; off < 16; off <<= 1)
#pragma unroll
      for (int r = 0; r < 4; ++r) mrow[r] = fmaxf(mrow[r], __shfl_xor(mrow[r], off));

    float alpha[4];
#pragma unroll
    for (int r = 0; r < 4; ++r) {
      const float mn = fmaxf(m_run[r], mrow[r]);
      alpha[r] = __expf(m_run[r] - mn);
      m_run[r] = mn;
    }
    float p[4][4], lsum[4] = {0.f, 0.f, 0.f, 0.f};
#pragma unroll
    for (int t = 0; t < 4; ++t)
#pragma unroll
      for (int r = 0; r < 4; ++r) {
        p[t][r] = __expf(s[t][r] - m_run[r]);
        lsum[r] += p[t][r];
      }
#pragma unroll
    for (int off = 1; off < 16; off <<= 1)
#pragma unroll
      for (int r = 0; r < 4; ++r) lsum[r] += __shfl_xor(lsum[r], off);
#pragma unroll
    for (int r = 0; r < 4; ++r) l_run[r] = l_run[r] * alpha[r] + lsum[r];
#pragma unroll
    for (int t = 0; t < 4; ++t)
#pragma unroll
      for (int r = 0; r < 4; ++r) oacc[t][r] *= alpha[r];

    // P -> per-wave LDS (bf16, [i][j] layout, stride 72)
#pragma unroll
    for (int t = 0; t < 4; ++t)
#pragma unroll
      for (int r = 0; r < 4; ++r)
        Ps[w][(quad * 4 + r) * 72 + t * 16 + col] = f2bf(p[t][r]);
    // wave-private region: in-wave DS ordering + compiler lgkmcnt suffice

    // PV: O[i][d] += P[i][j] * V[j][d]
#pragma unroll
    for (int ks = 0; ks < 2; ++ks) {
      const bf16x8 pf = *(const bf16x8*)(Ps[w] + col * 72 + ks * 32 + quad * 8);
#pragma unroll
      for (int nt = 0; nt < 4; ++nt) {
        const bf16x8 vf = *(const bf16x8*)(Vt + (nt * 16 + col) * 72 + ks * 32 + quad * 8);
        oacc[nt] = __builtin_amdgcn_mfma_f32_16x16x32_bf16(pf, vf, oacc[nt], 0, 0, 0);
      }
    }
  }

  // epilogue: o[i][h*64+d] = O/l
  float inv[4];
#pragma unroll
  for (int r = 0; r < 4; ++r) inv[r] = 1.0f / l_run[r];
  u16* ob = o + (size_t)z * S_ * V_ + h * HS_;
#pragma unroll
  for (int nt = 0; nt < 4; ++nt)
#pragma unroll
    for (int r = 0; r < 4; ++r)
      ob[(size_t)(irow + r) * V_ + nt * 16 + col] = f2bf(oacc[nt][r] * inv[r]);
}

// ---------------------------------------------------------------------------
// Output projection (vector NT-GEMM, known-good). out fp32.
// ---------------------------------------------------------------------------
__global__ __launch_bounds__(256) void oproj_vec_kernel(
    const u16* __restrict__ o, const void* __restrict__ w,
    float* __restrict__ out, const int* __restrict__ flag)
{
  __shared__ __align__(16) float At[64 * 68];
  __shared__ __align__(16) float Wt[64 * 68];
  const int tid = threadIdx.x;
  const size_t zo = (size_t)blockIdx.z * S_ * V_;
  const int m0 = blockIdx.x * 64;
  const int n0 = blockIdx.y * 64;
  const int tr = tid >> 4, tc = tid & 15;
  const int isf32 = *flag;
  const int srow = tid >> 2, sc = (tid & 3) * 16;

  float acc[4][4] = {};

  for (int k0 = 0; k0 < GK_; k0 += 64) {
    float av[16], wv[16];
    {
      const u16* gp = o + zo + (size_t)(m0 + srow) * GK_ + k0 + sc;
      uint4 u0 = *(const uint4*)gp;
      uint4 u1 = *(const uint4*)(gp + 8);
      av[0]=lo16(u0.x); av[1]=hi16(u0.x); av[2]=lo16(u0.y); av[3]=hi16(u0.y);
      av[4]=lo16(u0.z); av[5]=hi16(u0.z); av[6]=lo16(u0.w); av[7]=hi16(u0.w);
      av[8]=lo16(u1.x); av[9]=hi16(u1.x); av[10]=lo16(u1.y); av[11]=hi16(u1.y);
      av[12]=lo16(u1.z); av[13]=hi16(u1.z); av[14]=lo16(u1.w); av[15]=hi16(u1.w);
    }
    if (isf32) {
      const float4* gp = (const float4*)((const float*)w + (size_t)(n0 + srow) * GK_ + k0 + sc);
#pragma unroll
      for (int i = 0; i < 4; ++i) {
        float4 f = gp[i];
        wv[4*i+0]=f.x; wv[4*i+1]=f.y; wv[4*i+2]=f.z; wv[4*i+3]=f.w;
      }
    } else {
      const u16* gp = (const u16*)w + (size_t)(n0 + srow) * GK_ + k0 + sc;
      uint4 u0 = *(const uint4*)gp;
      uint4 u1 = *(const uint4*)(gp + 8);
      wv[0]=lo16(u0.x); wv[1]=hi16(u0.x); wv[2]=lo16(u0.y); wv[3]=hi16(u0.y);
      wv[4]=lo16(u0.z); wv[5]=hi16(u0.z); wv[6]=lo16(u0.w); wv[7]=hi16(u0.w);
      wv[8]=lo16(u1.x); wv[9]=hi16(u1.x); wv[10]=lo16(u1.y); wv[11]=hi16(u1.y);
      wv[12]=lo16(u1.z); wv[13]=hi16(u1.z); wv[14]=lo16(u1.w); wv[15]=hi16(u1.w);
    }
    __syncthreads();
#pragma unroll
    for (int i = 0; i < 16; ++i) {
      At[(sc + i) * 68 + srow] = av[i];
      Wt[(sc + i) * 68 + srow] = wv[i];
    }
    __syncthreads();

#pragma unroll 4
    for (int kk = 0; kk < 64; ++kk) {
      float4 a4 = *(const float4*)&At[kk * 68 + tr * 4];
      float4 w4 = *(const float4*)&Wt[kk * 68 + tc * 4];
      acc[0][0] += a4.x*w4.x; acc[0][1] += a4.x*w4.y; acc[0][2] += a4.x*w4.z; acc[0][3] += a4.x*w4.w;
      acc[1][0] += a4.y*w4.x; acc[1][1] += a4.y*w4.y; acc[1][2] += a4.y*w4.z; acc[1][3] += a4.y*w4.w;
      acc[2][0] += a4.z*w4.x; acc[2][1] += a4.z*w4.y; acc[2][2] += a4.z*w4.z; acc[2][3] += a4.z*w4.w;
      acc[3][0] += a4.w*w4.x; acc[3][1] += a4.w*w4.y; acc[3][2] += a4.w*w4.z; acc[3][3] += a4.w*w4.w;
    }
  }

#pragma unroll
  for (int r = 0; r < 4; ++r) {
    const int row = m0 + tr * 4 + r;
    *(float4*)(out + zo + (size_t)row * GN_ + n0 + tc * 4) =
        make_float4(acc[r][0], acc[r][1], acc[r][2], acc[r][3]);
  }
}

// ---------------------------------------------------------------------------
extern "C" void kernel_launch(void* const* d_in, const int* in_sizes, int n_in,
                              void* d_out, int out_size, void* d_ws, size_t ws_size,
                              hipStream_t stream) {
  const void* x = d_in[0];
  const void* wqkv = (n_in > 1) ? d_in[1] : d_in[0];
  const void* wout = (n_in > 2) ? d_in[2] : d_in[0];
  for (int i = 0; i < n_in; ++i) {
    if      (in_sizes[i] == B_ * S_ * V_)  x    = d_in[i];
    else if (in_sizes[i] == 3 * HS_ * HS_) wqkv = d_in[i];
    else if (in_sizes[i] == V_ * V_)       wout = d_in[i];
  }
  float* out = (float*)d_out;

  const size_t per_b = (size_t)H_ * S_ * HS_;   // 2,097,152 elems (4 MiB bf16)
  const size_t SV = (size_t)S_ * V_;
  int* flag = (int*)d_ws;
  // full mode: q,k,v,o each hold all 4 batches (16 MiB each) => 64 MiB + 16
  const bool full = ws_size >= (16 + 16 * per_b * sizeof(u16));
  const size_t stride = full ? 4 * per_b : per_b;
  u16* q = (u16*)((char*)d_ws + 16);
  u16* k = q + stride;
  u16* v = k + stride;
  u16* o = v + stride;
  const int zdim = full ? B_ : 1;
  const int nloop = full ? 1 : B_;

  detect_kernel<<<dim3(1), dim3(256), 0, stream>>>((const unsigned int*)x, flag);
  for (int l = 0; l < nloop; ++l) {
    const int b0 = full ? 0 : l;
    qkv_kernel<<<dim3(128, 1, zdim), dim3(256), 0, stream>>>(x, b0, wqkv, q, k, v, flag);
    attn_mfma_kernel<<<dim3(32, 16, zdim), dim3(256), 0, stream>>>(q, k, v, o);
    oproj_vec_kernel<<<dim3(32, 16, zdim), dim3(256), 0, stream>>>(
        o, wout, out + (size_t)b0 * SV, flag);
  }
}

// Round 9
// 378.522 us; speedup vs baseline: 9.3939x; 1.4567x over previous
//
#include <hip/hip_runtime.h>

// Causal MHA. B=4, S=2048, V=1024, H=16, hs=64. Output fp32.
// R9: MFMA output projection (128x128 tile, m93 structure) replaces vector
// oproj (was 250 us, MfmaUtil=0, 2.5e7 bank conflicts). attn/qkv unchanged.
#define B_  4
#define S_  2048
#define V_  1024
#define H_  16
#define HS_ 64
#define GK_ 1024
#define GN_ 1024

typedef unsigned short u16;
typedef __bf16 bf16x8 __attribute__((ext_vector_type(8)));
typedef float  f32x4  __attribute__((ext_vector_type(4)));

__device__ __forceinline__ float bf2f(u16 u) {
  return __uint_as_float(((unsigned int)u) << 16);
}
__device__ __forceinline__ float lo16(unsigned int w) { return __uint_as_float(w << 16); }
__device__ __forceinline__ float hi16(unsigned int w) { return __uint_as_float(w & 0xffff0000u); }
__device__ __forceinline__ u16 f2bf(float f) {
  unsigned int u = __float_as_uint(f);
  unsigned int r = u + 0x7fffu + ((u >> 16) & 1u);  // RNE
  return (u16)(r >> 16);
}

// ---------------------------------------------------------------------------
// Input-storage detector (fp32 vs bf16; see R5/R7 notes).
// ---------------------------------------------------------------------------
__global__ __launch_bounds__(256) void detect_kernel(
    const unsigned int* __restrict__ x32, int* __restrict__ flag)
{
  __shared__ int zred[256];
  __shared__ int nred[256];
  const int tid = threadIdx.x;
  int nz = 0, nn = 0;
  for (int i = tid; i < 16384; i += 256) {
    unsigned int lo = x32[i] & 0xffffu;
    if (lo == 0u) nz++;
    if ((lo & 0x7f80u) == 0x7f80u && (lo & 0x7fu) != 0u) nn++;
  }
  zred[tid] = nz; nred[tid] = nn;
  __syncthreads();
  for (int s = 128; s > 0; s >>= 1) {
    if (tid < s) { zred[tid] += zred[tid + s]; nred[tid] += nred[tid + s]; }
    __syncthreads();
  }
  if (tid == 0) *flag = (zred[0] > 8192 || nred[0] > 0) ? 1 : 0;
}

// ---------------------------------------------------------------------------
// W_out -> bf16 (into q's dead workspace region, full mode only).
// ---------------------------------------------------------------------------
__global__ __launch_bounds__(256) void wcvt_kernel(
    const void* __restrict__ w, u16* __restrict__ wb, const int* __restrict__ flag)
{
  const int i = (blockIdx.x * 256 + threadIdx.x) * 4;
  if (*flag) {
    float4 f = *(const float4*)((const float*)w + i);
    unsigned int p0 = (unsigned int)f2bf(f.x) | ((unsigned int)f2bf(f.y) << 16);
    unsigned int p1 = (unsigned int)f2bf(f.z) | ((unsigned int)f2bf(f.w) << 16);
    *(uint2*)(wb + i) = make_uint2(p0, p1);
  } else {
    *(uint2*)(wb + i) = *(const uint2*)((const u16*)w + i);
  }
}

// ---------------------------------------------------------------------------
// QKV projection, batch = b0 + blockIdx.z. q,k,v: [z][h][s][d] bf16.
// ---------------------------------------------------------------------------
__global__ __launch_bounds__(256) void qkv_kernel(
    const void* __restrict__ x, int b0, const void* __restrict__ w,
    u16* __restrict__ q, u16* __restrict__ k, u16* __restrict__ v,
    const int* __restrict__ flag)
{
  __shared__ __align__(16) float Ws[192 * 64];   // 48 KB
  const int tid = threadIdx.x;
  const int isf32 = *flag;
  if (isf32) {
    for (int i = tid; i < 192 * 64; i += 256) Ws[i] = ((const float*)w)[i];
  } else {
    for (int i = tid; i < 192 * 64; i += 256) Ws[i] = bf2f(((const u16*)w)[i]);
  }
  __syncthreads();

  const int th = blockIdx.x * 256 + tid;
  const int h = th & (H_ - 1);
  const int s = th >> 4;
  const int b = b0 + blockIdx.z;
  const size_t zoff = (size_t)blockIdx.z * H_ * S_ * HS_;
  const size_t xoff = ((size_t)b * S_ + s) * V_ + h * HS_;

  float xf[64];
  if (isf32) {
    const float4* xp = (const float4*)((const float*)x + xoff);
#pragma unroll
    for (int i = 0; i < 16; ++i) {
      float4 u = xp[i];
      xf[4*i+0] = u.x; xf[4*i+1] = u.y; xf[4*i+2] = u.z; xf[4*i+3] = u.w;
    }
  } else {
    const uint4* xp = (const uint4*)((const u16*)x + xoff);
#pragma unroll
    for (int i = 0; i < 8; ++i) {
      uint4 u = xp[i];
      xf[8*i+0] = lo16(u.x); xf[8*i+1] = hi16(u.x);
      xf[8*i+2] = lo16(u.y); xf[8*i+3] = hi16(u.y);
      xf[8*i+4] = lo16(u.z); xf[8*i+5] = hi16(u.z);
      xf[8*i+6] = lo16(u.w); xf[8*i+7] = hi16(u.w);
    }
  }

  const size_t obase = zoff + ((size_t)h * S_ + s) * HS_;
#pragma unroll 1
  for (int eg = 0; eg < 12; ++eg) {
    float acc[16];
#pragma unroll
    for (int ee = 0; ee < 16; ++ee) {
      const float4* wr = (const float4*)&Ws[(eg * 16 + ee) * 64];
      float a = 0.f;
#pragma unroll
      for (int d4 = 0; d4 < 16; ++d4) {
        float4 wv = wr[d4];
        a += xf[d4*4+0]*wv.x + xf[d4*4+1]*wv.y + xf[d4*4+2]*wv.z + xf[d4*4+3]*wv.w;
      }
      acc[ee] = a;
    }
    u16* dst = (eg < 4) ? q : (eg < 8) ? k : v;
    const int d0 = (eg & 3) * 16;
    unsigned int p[8];
#pragma unroll
    for (int t = 0; t < 8; ++t)
      p[t] = (unsigned int)f2bf(acc[2*t]) | ((unsigned int)f2bf(acc[2*t+1]) << 16);
    uint4* dp = (uint4*)(dst + obase + d0);
    dp[0] = make_uint4(p[0], p[1], p[2], p[3]);
    dp[1] = make_uint4(p[4], p[5], p[6], p[7]);
  }
}

// ---------------------------------------------------------------------------
// MFMA flash attention (R8, unchanged). Block = 4 waves = 64 Q rows.
// ---------------------------------------------------------------------------
__global__ __launch_bounds__(256) void attn_mfma_kernel(
    const u16* __restrict__ q, const u16* __restrict__ k,
    const u16* __restrict__ v, u16* __restrict__ o)
{
  const int z   = blockIdx.z;
  const int h   = blockIdx.y;
  int qq = (blockIdx.x + 8 * z) & 31;
  if (h & 8) qq = 31 - qq;
  const int qb  = qq * 64;
  const int tid = threadIdx.x;
  const int w = tid >> 6, lane = tid & 63;
  const int col = lane & 15, quad = lane >> 4;

  __shared__ __align__(16) u16 Ks[64 * 72];
  __shared__ __align__(16) u16 Vt[64 * 72];
  __shared__ __align__(16) u16 Ps[4][16 * 72];

  const size_t hs = ((size_t)z * H_ + h) * S_ * HS_;

  bf16x8 qf[2];
  {
    const u16* qp = q + hs + (size_t)(qb + w * 16 + col) * HS_ + quad * 8;
#pragma unroll
    for (int ks = 0; ks < 2; ++ks) {
      u16 t8[8];
      *(uint4*)t8 = *(const uint4*)(qp + ks * 32);
#pragma unroll
      for (int e = 0; e < 8; ++e) t8[e] = f2bf(bf2f(t8[e]) * 0.125f);
      qf[ks] = *(bf16x8*)t8;
    }
  }

  const int sr = tid >> 2, sc = (tid & 3) * 16;
  const int vrow = tid & 63, vc = (tid >> 6) * 16;
  const int irow = qb + w * 16 + quad * 4;

  f32x4 oacc[4] = {};
  float m_run[4] = {-INFINITY, -INFINITY, -INFINITY, -INFINITY};
  float l_run[4] = {0.f, 0.f, 0.f, 0.f};

  for (int jb = 0; jb <= qb; jb += 64) {
    const u16* kp = k + hs + (size_t)(jb + sr) * HS_ + sc;
    uint4 k0 = *(const uint4*)kp;
    uint4 k1 = *(const uint4*)(kp + 8);
    const u16* vp = v + hs + (size_t)(jb + vrow) * HS_ + vc;
    uint4 v0 = *(const uint4*)vp;
    uint4 v1 = *(const uint4*)(vp + 8);
    __syncthreads();
    *(uint4*)(Ks + sr * 72 + sc)     = k0;
    *(uint4*)(Ks + sr * 72 + sc + 8) = k1;
    {
      u16 t16[16];
      *(uint4*)t16 = v0; *(uint4*)(t16 + 8) = v1;
#pragma unroll
      for (int e = 0; e < 16; ++e) Vt[(vc + e) * 72 + vrow] = t16[e];
    }
    __syncthreads();

    f32x4 sacc[4] = {};
#pragma unroll
    for (int ks = 0; ks < 2; ++ks)
#pragma unroll
      for (int t = 0; t < 4; ++t) {
        const bf16x8 kf = *(const bf16x8*)(Ks + (t * 16 + col) * 72 + ks * 32 + quad * 8);
        sacc[t] = __builtin_amdgcn_mfma_f32_16x16x32_bf16(qf[ks], kf, sacc[t], 0, 0, 0);
      }

    float s[4][4];
#pragma unroll
    for (int t = 0; t < 4; ++t)
#pragma unroll
      for (int r = 0; r < 4; ++r) s[t][r] = sacc[t][r];

    if (jb == qb) {
#pragma unroll
      for (int t = 0; t < 4; ++t) {
        const int j = jb + t * 16 + col;
#pragma unroll
        for (int r = 0; r < 4; ++r)
          if (j > irow + r) s[t][r] = -INFINITY;
      }
    }

    float mrow[4];
#pragma unroll
    for (int r = 0; r < 4; ++r)
      mrow[r] = fmaxf(fmaxf(s[0][r], s[1][r]), fmaxf(s[2][r], s[3][r]));
#pragma unroll
    for (int off = 1; off < 16; off <<= 1)
#pragma unroll
      for (int r = 0; r < 4; ++r) mrow[r] = fmaxf(mrow[r], __shfl_xor(mrow[r], off));

    float alpha[4];
#pragma unroll
    for (int r = 0; r < 4; ++r) {
      const float mn = fmaxf(m_run[r], mrow[r]);
      alpha[r] = __expf(m_run[r] - mn);
      m_run[r] = mn;
    }
    float p[4][4], lsum[4] = {0.f, 0.f, 0.f, 0.f};
#pragma unroll
    for (int t = 0; t < 4; ++t)
#pragma unroll
      for (int r = 0; r < 4; ++r) {
        p[t][r] = __expf(s[t][r] - m_run[r]);
        lsum[r] += p[t][r];
      }
#pragma unroll
    for (int off = 1; off < 16; off <<= 1)
#pragma unroll
      for (int r = 0; r < 4; ++r) lsum[r] += __shfl_xor(lsum[r], off);
#pragma unroll
    for (int r = 0; r < 4; ++r) l_run[r] = l_run[r] * alpha[r] + lsum[r];
#pragma unroll
    for (int t = 0; t < 4; ++t)
#pragma unroll
      for (int r = 0; r < 4; ++r) oacc[t][r] *= alpha[r];

#pragma unroll
    for (int t = 0; t < 4; ++t)
#pragma unroll
      for (int r = 0; r < 4; ++r)
        Ps[w][(quad * 4 + r) * 72 + t * 16 + col] = f2bf(p[t][r]);

#pragma unroll
    for (int ks = 0; ks < 2; ++ks) {
      const bf16x8 pf = *(const bf16x8*)(Ps[w] + col * 72 + ks * 32 + quad * 8);
#pragma unroll
      for (int nt = 0; nt < 4; ++nt) {
        const bf16x8 vf = *(const bf16x8*)(Vt + (nt * 16 + col) * 72 + ks * 32 + quad * 8);
        oacc[nt] = __builtin_amdgcn_mfma_f32_16x16x32_bf16(pf, vf, oacc[nt], 0, 0, 0);
      }
    }
  }

  float inv[4];
#pragma unroll
  for (int r = 0; r < 4; ++r) inv[r] = 1.0f / l_run[r];
  u16* ob = o + (size_t)z * S_ * V_ + h * HS_;
#pragma unroll
  for (int nt = 0; nt < 4; ++nt)
#pragma unroll
    for (int r = 0; r < 4; ++r)
      ob[(size_t)(irow + r) * V_ + nt * 16 + col] = f2bf(oacc[nt][r] * inv[r]);
}

// ---------------------------------------------------------------------------
// Output projection, MFMA NT-GEMM (m93 structure). M=8192 (all batches),
// N=K=1024. 128x128 tile, BK=32, 4 waves in 2x2 quadrants, 4x4 acc each.
// LDS stride 40 elems (80 B): full 32-bank coverage, <=2-way alias (free).
// C/D mapping: col=lane&15 (n), row=quad*4+reg (m)  [m89/m91 verified].
// ---------------------------------------------------------------------------
__global__ __launch_bounds__(256) void oproj_mfma_kernel(
    const u16* __restrict__ a,   // o  [M][1024] bf16
    const u16* __restrict__ bw,  // wb [1024][1024] bf16
    float* __restrict__ c)       // out [M][1024] fp32
{
  __shared__ __align__(16) u16 As[128 * 40];   // 10 KB
  __shared__ __align__(16) u16 Bs[128 * 40];   // 10 KB
  const int tid = threadIdx.x;
  const int m0 = blockIdx.x * 128;
  const int n0 = blockIdx.y * 128;
  const int w = tid >> 6, lane = tid & 63;
  const int col = lane & 15, quad = lane >> 4;
  const int qr = (w & 1) * 64;    // wave row quadrant
  const int qc = (w >> 1) * 64;   // wave col quadrant

  f32x4 acc[4][4] = {};

  const int sr = tid >> 2;            // 0..63
  const int sk = (tid & 3) * 8;       // 0,8,16,24
  const u16* ga = a  + (size_t)(m0 + sr) * GK_ + sk;
  const u16* gb = bw + (size_t)(n0 + sr) * GK_ + sk;

  for (int k0 = 0; k0 < GK_; k0 += 32) {
    uint4 a0 = *(const uint4*)(ga + k0);
    uint4 a1 = *(const uint4*)(ga + (size_t)64 * GK_ + k0);
    uint4 b0 = *(const uint4*)(gb + k0);
    uint4 b1 = *(const uint4*)(gb + (size_t)64 * GK_ + k0);
    __syncthreads();                      // prior frag reads done
    *(uint4*)(As + sr * 40 + sk)        = a0;
    *(uint4*)(As + (64 + sr) * 40 + sk) = a1;
    *(uint4*)(Bs + sr * 40 + sk)        = b0;
    *(uint4*)(Bs + (64 + sr) * 40 + sk) = b1;
    __syncthreads();                      // tile visible

    bf16x8 af[4], bf[4];
#pragma unroll
    for (int i = 0; i < 4; ++i) {
      af[i] = *(const bf16x8*)(As + (qr + i * 16 + col) * 40 + quad * 8);
      bf[i] = *(const bf16x8*)(Bs + (qc + i * 16 + col) * 40 + quad * 8);
    }
#pragma unroll
    for (int i = 0; i < 4; ++i)
#pragma unroll
      for (int j = 0; j < 4; ++j)
        acc[i][j] = __builtin_amdgcn_mfma_f32_16x16x32_bf16(af[i], bf[j], acc[i][j], 0, 0, 0);
  }

#pragma unroll
  for (int i = 0; i < 4; ++i)
#pragma unroll
    for (int j = 0; j < 4; ++j)
#pragma unroll
      for (int r = 0; r < 4; ++r)
        c[(size_t)(m0 + qr + i * 16 + quad * 4 + r) * GN_ + n0 + qc + j * 16 + col]
            = acc[i][j][r];
}

// ---------------------------------------------------------------------------
// Fallback vector oproj (per-batch mode only).
// ---------------------------------------------------------------------------
__global__ __launch_bounds__(256) void oproj_vec_kernel(
    const u16* __restrict__ o, const void* __restrict__ w,
    float* __restrict__ out, const int* __restrict__ flag)
{
  __shared__ __align__(16) float At[64 * 68];
  __shared__ __align__(16) float Wt[64 * 68];
  const int tid = threadIdx.x;
  const size_t zo = (size_t)blockIdx.z * S_ * V_;
  const int m0 = blockIdx.x * 64;
  const int n0 = blockIdx.y * 64;
  const int tr = tid >> 4, tc = tid & 15;
  const int isf32 = *flag;
  const int srow = tid >> 2, sc = (tid & 3) * 16;

  float acc[4][4] = {};

  for (int k0 = 0; k0 < GK_; k0 += 64) {
    float av[16], wv[16];
    {
      const u16* gp = o + zo + (size_t)(m0 + srow) * GK_ + k0 + sc;
      uint4 u0 = *(const uint4*)gp;
      uint4 u1 = *(const uint4*)(gp + 8);
      av[0]=lo16(u0.x); av[1]=hi16(u0.x); av[2]=lo16(u0.y); av[3]=hi16(u0.y);
      av[4]=lo16(u0.z); av[5]=hi16(u0.z); av[6]=lo16(u0.w); av[7]=hi16(u0.w);
      av[8]=lo16(u1.x); av[9]=hi16(u1.x); av[10]=lo16(u1.y); av[11]=hi16(u1.y);
      av[12]=lo16(u1.z); av[13]=hi16(u1.z); av[14]=lo16(u1.w); av[15]=hi16(u1.w);
    }
    if (isf32) {
      const float4* gp = (const float4*)((const float*)w + (size_t)(n0 + srow) * GK_ + k0 + sc);
#pragma unroll
      for (int i = 0; i < 4; ++i) {
        float4 f = gp[i];
        wv[4*i+0]=f.x; wv[4*i+1]=f.y; wv[4*i+2]=f.z; wv[4*i+3]=f.w;
      }
    } else {
      const u16* gp = (const u16*)w + (size_t)(n0 + srow) * GK_ + k0 + sc;
      uint4 u0 = *(const uint4*)gp;
      uint4 u1 = *(const uint4*)(gp + 8);
      wv[0]=lo16(u0.x); wv[1]=hi16(u0.x); wv[2]=lo16(u0.y); wv[3]=hi16(u0.y);
      wv[4]=lo16(u0.z); wv[5]=hi16(u0.z); wv[6]=lo16(u0.w); wv[7]=hi16(u0.w);
      wv[8]=lo16(u1.x); wv[9]=hi16(u1.x); wv[10]=lo16(u1.y); wv[11]=hi16(u1.y);
      wv[12]=lo16(u1.z); wv[13]=hi16(u1.z); wv[14]=lo16(u1.w); wv[15]=hi16(u1.w);
    }
    __syncthreads();
#pragma unroll
    for (int i = 0; i < 16; ++i) {
      At[(sc + i) * 68 + srow] = av[i];
      Wt[(sc + i) * 68 + srow] = wv[i];
    }
    __syncthreads();

#pragma unroll 4
    for (int kk = 0; kk < 64; ++kk) {
      float4 a4 = *(const float4*)&At[kk * 68 + tr * 4];
      float4 w4 = *(const float4*)&Wt[kk * 68 + tc * 4];
      acc[0][0] += a4.x*w4.x; acc[0][1] += a4.x*w4.y; acc[0][2] += a4.x*w4.z; acc[0][3] += a4.x*w4.w;
      acc[1][0] += a4.y*w4.x; acc[1][1] += a4.y*w4.y; acc[1][2] += a4.y*w4.z; acc[1][3] += a4.y*w4.w;
      acc[2][0] += a4.z*w4.x; acc[2][1] += a4.z*w4.y; acc[2][2] += a4.z*w4.z; acc[2][3] += a4.z*w4.w;
      acc[3][0] += a4.w*w4.x; acc[3][1] += a4.w*w4.y; acc[3][2] += a4.w*w4.z; acc[3][3] += a4.w*w4.w;
    }
  }

#pragma unroll
  for (int r = 0; r < 4; ++r) {
    const int row = m0 + tr * 4 + r;
    *(float4*)(out + zo + (size_t)row * GN_ + n0 + tc * 4) =
        make_float4(acc[r][0], acc[r][1], acc[r][2], acc[r][3]);
  }
}

// ---------------------------------------------------------------------------
extern "C" void kernel_launch(void* const* d_in, const int* in_sizes, int n_in,
                              void* d_out, int out_size, void* d_ws, size_t ws_size,
                              hipStream_t stream) {
  const void* x = d_in[0];
  const void* wqkv = (n_in > 1) ? d_in[1] : d_in[0];
  const void* wout = (n_in > 2) ? d_in[2] : d_in[0];
  for (int i = 0; i < n_in; ++i) {
    if      (in_sizes[i] == B_ * S_ * V_)  x    = d_in[i];
    else if (in_sizes[i] == 3 * HS_ * HS_) wqkv = d_in[i];
    else if (in_sizes[i] == V_ * V_)       wout = d_in[i];
  }
  float* out = (float*)d_out;

  const size_t per_b = (size_t)H_ * S_ * HS_;   // 2,097,152 elems (4 MiB bf16)
  const size_t SV = (size_t)S_ * V_;
  int* flag = (int*)d_ws;
  const bool full = ws_size >= (16 + 16 * per_b * sizeof(u16));
  const size_t stride = full ? 4 * per_b : per_b;
  u16* q = (u16*)((char*)d_ws + 16);
  u16* k = q + stride;
  u16* v = k + stride;
  u16* o = v + stride;

  detect_kernel<<<dim3(1), dim3(256), 0, stream>>>((const unsigned int*)x, flag);
  if (full) {
    qkv_kernel<<<dim3(128, 1, B_), dim3(256), 0, stream>>>(x, 0, wqkv, q, k, v, flag);
    attn_mfma_kernel<<<dim3(32, 16, B_), dim3(256), 0, stream>>>(q, k, v, o);
    // q is dead after attn: reuse its region for bf16 W_out (2 MiB <= 16 MiB)
    u16* wb = q;
    wcvt_kernel<<<dim3((V_ * V_) / 1024), dim3(256), 0, stream>>>(wout, wb, flag);
    oproj_mfma_kernel<<<dim3((B_ * S_) / 128, GN_ / 128), dim3(256), 0, stream>>>(o, wb, out);
  } else {
    for (int b = 0; b < B_; ++b) {
      qkv_kernel<<<dim3(128, 1, 1), dim3(256), 0, stream>>>(x, b, wqkv, q, k, v, flag);
      attn_mfma_kernel<<<dim3(32, 16, 1), dim3(256), 0, stream>>>(q, k, v, o);
      oproj_vec_kernel<<<dim3(32, 16, 1), dim3(256), 0, stream>>>(
          o, wout, out + (size_t)b * SV, flag);
    }
  }
}

// Round 10
// 296.770 us; speedup vs baseline: 11.9816x; 1.2755x over previous
//
#include <hip/hip_runtime.h>

// Causal MHA. B=4, S=2048, V=1024, H=16, hs=64. Output fp32.
// R10: MFMA qkv projection (NT-GEMM M=131072,N=192,K=64; x IS A[131072][64]
// contiguous) replaces the LDS-read-bound vector qkv (~140 us). attn/oproj
// unchanged.
#define B_  4
#define S_  2048
#define V_  1024
#define H_  16
#define HS_ 64
#define GK_ 1024
#define GN_ 1024

typedef unsigned short u16;
typedef __bf16 bf16x8 __attribute__((ext_vector_type(8)));
typedef float  f32x4  __attribute__((ext_vector_type(4)));

__device__ __forceinline__ float bf2f(u16 u) {
  return __uint_as_float(((unsigned int)u) << 16);
}
__device__ __forceinline__ float lo16(unsigned int w) { return __uint_as_float(w << 16); }
__device__ __forceinline__ float hi16(unsigned int w) { return __uint_as_float(w & 0xffff0000u); }
__device__ __forceinline__ u16 f2bf(float f) {
  unsigned int u = __float_as_uint(f);
  unsigned int r = u + 0x7fffu + ((u >> 16) & 1u);  // RNE
  return (u16)(r >> 16);
}

// ---------------------------------------------------------------------------
// Input-storage detector (fp32 vs bf16; see R5/R7 notes).
// ---------------------------------------------------------------------------
__global__ __launch_bounds__(256) void detect_kernel(
    const unsigned int* __restrict__ x32, int* __restrict__ flag)
{
  __shared__ int zred[256];
  __shared__ int nred[256];
  const int tid = threadIdx.x;
  int nz = 0, nn = 0;
  for (int i = tid; i < 16384; i += 256) {
    unsigned int lo = x32[i] & 0xffffu;
    if (lo == 0u) nz++;
    if ((lo & 0x7f80u) == 0x7f80u && (lo & 0x7fu) != 0u) nn++;
  }
  zred[tid] = nz; nred[tid] = nn;
  __syncthreads();
  for (int s = 128; s > 0; s >>= 1) {
    if (tid < s) { zred[tid] += zred[tid + s]; nred[tid] += nred[tid + s]; }
    __syncthreads();
  }
  if (tid == 0) *flag = (zred[0] > 8192 || nred[0] > 0) ? 1 : 0;
}

// ---------------------------------------------------------------------------
// W_out -> bf16 (into q's dead workspace region, full mode only).
// ---------------------------------------------------------------------------
__global__ __launch_bounds__(256) void wcvt_kernel(
    const void* __restrict__ w, u16* __restrict__ wb, const int* __restrict__ flag)
{
  const int i = (blockIdx.x * 256 + threadIdx.x) * 4;
  if (*flag) {
    float4 f = *(const float4*)((const float*)w + i);
    unsigned int p0 = (unsigned int)f2bf(f.x) | ((unsigned int)f2bf(f.y) << 16);
    unsigned int p1 = (unsigned int)f2bf(f.z) | ((unsigned int)f2bf(f.w) << 16);
    *(uint2*)(wb + i) = make_uint2(p0, p1);
  } else {
    *(uint2*)(wb + i) = *(const uint2*)((const u16*)w + i);
  }
}

// ---------------------------------------------------------------------------
// R10: MFMA QKV projection. C[m][e] = sum_d A[m][d] * W[e][d], m=131072,
// e=192, d=64. A = x reshaped [131072][64] (contiguous). Block: 128 rows x
// 192 cols, 4 waves in 2x3... actually 2 row-halves x 2 col-halves of 96.
// A-frags loaded direct from global (fp32->bf16 in regs); W in LDS stride 80.
// C/D: col=lane&15 (e), row=quad*4+r (m)  [m89/m91]. Scatter to [z][h][s][d].
// ---------------------------------------------------------------------------
__global__ __launch_bounds__(256) void qkv_mfma_kernel(
    const void* __restrict__ x, const void* __restrict__ wqkv,
    u16* __restrict__ q, u16* __restrict__ k, u16* __restrict__ v,
    const int* __restrict__ flag)
{
  __shared__ __align__(16) u16 Ws[192 * 80];   // 30720 B
  const int tid = threadIdx.x;
  const int isf32 = *flag;
  for (int idx = tid; idx < 192 * 4; idx += 256) {
    const int row = idx >> 2, c0 = (idx & 3) * 16;
    u16 t16[16];
    if (isf32) {
      const float* gp = (const float*)wqkv + row * 64 + c0;
#pragma unroll
      for (int e = 0; e < 16; ++e) t16[e] = f2bf(gp[e]);
    } else {
      const u16* gp = (const u16*)wqkv + row * 64 + c0;
      *(uint4*)t16 = *(const uint4*)gp;
      *(uint4*)(t16 + 8) = *(const uint4*)(gp + 8);
    }
    *(uint4*)(Ws + row * 80 + c0) = *(uint4*)t16;
    *(uint4*)(Ws + row * 80 + c0 + 8) = *(uint4*)(t16 + 8);
  }
  __syncthreads();

  const int m0 = blockIdx.x * 128;
  const int w = tid >> 6, lane = tid & 63;
  const int ar = lane & 15, quad = lane >> 4;
  const int rbase = m0 + (w & 1) * 64;     // wave rows (4 row-tiles)
  const int cbase = (w >> 1) * 96;         // wave cols (6 col-tiles)

  // A fragments direct from global: [m=ar][k=ks*32+quad*8+j]
  bf16x8 af[4][2];
#pragma unroll
  for (int rt = 0; rt < 4; ++rt) {
    const size_t row = (size_t)(rbase + rt * 16 + ar) * 64;
    if (isf32) {
      const float* gp = (const float*)x + row;
#pragma unroll
      for (int ks = 0; ks < 2; ++ks) {
        u16 t8[8];
        const float* g8 = gp + ks * 32 + quad * 8;
#pragma unroll
        for (int e = 0; e < 8; ++e) t8[e] = f2bf(g8[e]);
        af[rt][ks] = *(bf16x8*)t8;
      }
    } else {
      const u16* gp = (const u16*)x + row;
#pragma unroll
      for (int ks = 0; ks < 2; ++ks)
        af[rt][ks] = *(const bf16x8*)(gp + ks * 32 + quad * 8);
    }
  }

  f32x4 acc[4][6] = {};
#pragma unroll
  for (int ks = 0; ks < 2; ++ks)
#pragma unroll
    for (int t = 0; t < 6; ++t) {
      const bf16x8 bfr = *(const bf16x8*)(Ws + (cbase + t * 16 + ar) * 80 + ks * 32 + quad * 8);
#pragma unroll
      for (int rt = 0; rt < 4; ++rt)
        acc[rt][t] = __builtin_amdgcn_mfma_f32_16x16x32_bf16(af[rt][ks], bfr, acc[rt][t], 0, 0, 0);
    }

  // epilogue: m -> (z, s, h); e -> (matrix, d)
#pragma unroll
  for (int rt = 0; rt < 4; ++rt)
#pragma unroll
    for (int r = 0; r < 4; ++r) {
      const int m = rbase + rt * 16 + quad * 4 + r;
      const int z = m >> 15, s = (m >> 4) & (S_ - 1), h = m & (H_ - 1);
      const size_t base = (((size_t)z * H_ + h) * S_ + s) * HS_;
#pragma unroll
      for (int t = 0; t < 6; ++t) {
        const int e = cbase + t * 16 + ar;
        u16* dst = (e < 64) ? q : (e < 128) ? k : v;
        dst[base + (e & 63)] = f2bf(acc[rt][t][r]);
      }
    }
}

// ---------------------------------------------------------------------------
// Fallback vector QKV (per-batch mode only; unchanged from R9).
// ---------------------------------------------------------------------------
__global__ __launch_bounds__(256) void qkv_kernel(
    const void* __restrict__ x, int b0, const void* __restrict__ w,
    u16* __restrict__ q, u16* __restrict__ k, u16* __restrict__ v,
    const int* __restrict__ flag)
{
  __shared__ __align__(16) float Ws[192 * 64];
  const int tid = threadIdx.x;
  const int isf32 = *flag;
  if (isf32) {
    for (int i = tid; i < 192 * 64; i += 256) Ws[i] = ((const float*)w)[i];
  } else {
    for (int i = tid; i < 192 * 64; i += 256) Ws[i] = bf2f(((const u16*)w)[i]);
  }
  __syncthreads();

  const int th = blockIdx.x * 256 + tid;
  const int h = th & (H_ - 1);
  const int s = th >> 4;
  const int b = b0 + blockIdx.z;
  const size_t zoff = (size_t)blockIdx.z * H_ * S_ * HS_;
  const size_t xoff = ((size_t)b * S_ + s) * V_ + h * HS_;

  float xf[64];
  if (isf32) {
    const float4* xp = (const float4*)((const float*)x + xoff);
#pragma unroll
    for (int i = 0; i < 16; ++i) {
      float4 u = xp[i];
      xf[4*i+0] = u.x; xf[4*i+1] = u.y; xf[4*i+2] = u.z; xf[4*i+3] = u.w;
    }
  } else {
    const uint4* xp = (const uint4*)((const u16*)x + xoff);
#pragma unroll
    for (int i = 0; i < 8; ++i) {
      uint4 u = xp[i];
      xf[8*i+0] = lo16(u.x); xf[8*i+1] = hi16(u.x);
      xf[8*i+2] = lo16(u.y); xf[8*i+3] = hi16(u.y);
      xf[8*i+4] = lo16(u.z); xf[8*i+5] = hi16(u.z);
      xf[8*i+6] = lo16(u.w); xf[8*i+7] = hi16(u.w);
    }
  }

  const size_t obase = zoff + ((size_t)h * S_ + s) * HS_;
#pragma unroll 1
  for (int eg = 0; eg < 12; ++eg) {
    float acc[16];
#pragma unroll
    for (int ee = 0; ee < 16; ++ee) {
      const float4* wr = (const float4*)&Ws[(eg * 16 + ee) * 64];
      float a = 0.f;
#pragma unroll
      for (int d4 = 0; d4 < 16; ++d4) {
        float4 wv = wr[d4];
        a += xf[d4*4+0]*wv.x + xf[d4*4+1]*wv.y + xf[d4*4+2]*wv.z + xf[d4*4+3]*wv.w;
      }
      acc[ee] = a;
    }
    u16* dst = (eg < 4) ? q : (eg < 8) ? k : v;
    const int d0 = (eg & 3) * 16;
    unsigned int p[8];
#pragma unroll
    for (int t = 0; t < 8; ++t)
      p[t] = (unsigned int)f2bf(acc[2*t]) | ((unsigned int)f2bf(acc[2*t+1]) << 16);
    uint4* dp = (uint4*)(dst + obase + d0);
    dp[0] = make_uint4(p[0], p[1], p[2], p[3]);
    dp[1] = make_uint4(p[4], p[5], p[6], p[7]);
  }
}

// ---------------------------------------------------------------------------
// MFMA flash attention (R8, unchanged). Block = 4 waves = 64 Q rows.
// ---------------------------------------------------------------------------
__global__ __launch_bounds__(256) void attn_mfma_kernel(
    const u16* __restrict__ q, const u16* __restrict__ k,
    const u16* __restrict__ v, u16* __restrict__ o)
{
  const int z   = blockIdx.z;
  const int h   = blockIdx.y;
  int qq = (blockIdx.x + 8 * z) & 31;
  if (h & 8) qq = 31 - qq;
  const int qb  = qq * 64;
  const int tid = threadIdx.x;
  const int w = tid >> 6, lane = tid & 63;
  const int col = lane & 15, quad = lane >> 4;

  __shared__ __align__(16) u16 Ks[64 * 72];
  __shared__ __align__(16) u16 Vt[64 * 72];
  __shared__ __align__(16) u16 Ps[4][16 * 72];

  const size_t hs = ((size_t)z * H_ + h) * S_ * HS_;

  bf16x8 qf[2];
  {
    const u16* qp = q + hs + (size_t)(qb + w * 16 + col) * HS_ + quad * 8;
#pragma unroll
    for (int ks = 0; ks < 2; ++ks) {
      u16 t8[8];
      *(uint4*)t8 = *(const uint4*)(qp + ks * 32);
#pragma unroll
      for (int e = 0; e < 8; ++e) t8[e] = f2bf(bf2f(t8[e]) * 0.125f);
      qf[ks] = *(bf16x8*)t8;
    }
  }

  const int sr = tid >> 2, sc = (tid & 3) * 16;
  const int vrow = tid & 63, vc = (tid >> 6) * 16;
  const int irow = qb + w * 16 + quad * 4;

  f32x4 oacc[4] = {};
  float m_run[4] = {-INFINITY, -INFINITY, -INFINITY, -INFINITY};
  float l_run[4] = {0.f, 0.f, 0.f, 0.f};

  for (int jb = 0; jb <= qb; jb += 64) {
    const u16* kp = k + hs + (size_t)(jb + sr) * HS_ + sc;
    uint4 k0 = *(const uint4*)kp;
    uint4 k1 = *(const uint4*)(kp + 8);
    const u16* vp = v + hs + (size_t)(jb + vrow) * HS_ + vc;
    uint4 v0 = *(const uint4*)vp;
    uint4 v1 = *(const uint4*)(vp + 8);
    __syncthreads();
    *(uint4*)(Ks + sr * 72 + sc)     = k0;
    *(uint4*)(Ks + sr * 72 + sc + 8) = k1;
    {
      u16 t16[16];
      *(uint4*)t16 = v0; *(uint4*)(t16 + 8) = v1;
#pragma unroll
      for (int e = 0; e < 16; ++e) Vt[(vc + e) * 72 + vrow] = t16[e];
    }
    __syncthreads();

    f32x4 sacc[4] = {};
#pragma unroll
    for (int ks = 0; ks < 2; ++ks)
#pragma unroll
      for (int t = 0; t < 4; ++t) {
        const bf16x8 kf = *(const bf16x8*)(Ks + (t * 16 + col) * 72 + ks * 32 + quad * 8);
        sacc[t] = __builtin_amdgcn_mfma_f32_16x16x32_bf16(qf[ks], kf, sacc[t], 0, 0, 0);
      }

    float s[4][4];
#pragma unroll
    for (int t = 0; t < 4; ++t)
#pragma unroll
      for (int r = 0; r < 4; ++r) s[t][r] = sacc[t][r];

    if (jb == qb) {
#pragma unroll
      for (int t = 0; t < 4; ++t) {
        const int j = jb + t * 16 + col;
#pragma unroll
        for (int r = 0; r < 4; ++r)
          if (j > irow + r) s[t][r] = -INFINITY;
      }
    }

    float mrow[4];
#pragma unroll
    for (int r = 0; r < 4; ++r)
      mrow[r] = fmaxf(fmaxf(s[0][r], s[1][r]), fmaxf(s[2][r], s[3][r]));
#pragma unroll
    for (int off = 1; off < 16; off <<= 1)
#pragma unroll
      for (int r = 0; r < 4; ++r) mrow[r] = fmaxf(mrow[r], __shfl_xor(mrow[r], off));

    float alpha[4];
#pragma unroll
    for (int r = 0; r < 4; ++r) {
      const float mn = fmaxf(m_run[r], mrow[r]);
      alpha[r] = __expf(m_run[r] - mn);
      m_run[r] = mn;
    }
    float p[4][4], lsum[4] = {0.f, 0.f, 0.f, 0.f};
#pragma unroll
    for (int t = 0; t < 4; ++t)
#pragma unroll
      for (int r = 0; r < 4; ++r) {
        p[t][r] = __expf(s[t][r] - m_run[r]);
        lsum[r] += p[t][r];
      }
#pragma unroll
    for (int off = 1; off < 16; off <<= 1)
#pragma unroll
      for (int r = 0; r < 4; ++r) lsum[r] += __shfl_xor(lsum[r], off);
#pragma unroll
    for (int r = 0; r < 4; ++r) l_run[r] = l_run[r] * alpha[r] + lsum[r];
#pragma unroll
    for (int t = 0; t < 4; ++t)
#pragma unroll
      for (int r = 0; r < 4; ++r) oacc[t][r] *= alpha[r];

#pragma unroll
    for (int t = 0; t < 4; ++t)
#pragma unroll
      for (int r = 0; r < 4; ++r)
        Ps[w][(quad * 4 + r) * 72 + t * 16 + col] = f2bf(p[t][r]);

#pragma unroll
    for (int ks = 0; ks < 2; ++ks) {
      const bf16x8 pf = *(const bf16x8*)(Ps[w] + col * 72 + ks * 32 + quad * 8);
#pragma unroll
      for (int nt = 0; nt < 4; ++nt) {
        const bf16x8 vf = *(const bf16x8*)(Vt + (nt * 16 + col) * 72 + ks * 32 + quad * 8);
        oacc[nt] = __builtin_amdgcn_mfma_f32_16x16x32_bf16(pf, vf, oacc[nt], 0, 0, 0);
      }
    }
  }

  float inv[4];
#pragma unroll
  for (int r = 0; r < 4; ++r) inv[r] = 1.0f / l_run[r];
  u16* ob = o + (size_t)z * S_ * V_ + h * HS_;
#pragma unroll
  for (int nt = 0; nt < 4; ++nt)
#pragma unroll
    for (int r = 0; r < 4; ++r)
      ob[(size_t)(irow + r) * V_ + nt * 16 + col] = f2bf(oacc[nt][r] * inv[r]);
}

// ---------------------------------------------------------------------------
// Output projection, MFMA NT-GEMM (R9, unchanged). 128x128 tile, BK=32.
// ---------------------------------------------------------------------------
__global__ __launch_bounds__(256) void oproj_mfma_kernel(
    const u16* __restrict__ a, const u16* __restrict__ bw, float* __restrict__ c)
{
  __shared__ __align__(16) u16 As[128 * 40];
  __shared__ __align__(16) u16 Bs[128 * 40];
  const int tid = threadIdx.x;
  const int m0 = blockIdx.x * 128;
  const int n0 = blockIdx.y * 128;
  const int w = tid >> 6, lane = tid & 63;
  const int col = lane & 15, quad = lane >> 4;
  const int qr = (w & 1) * 64;
  const int qc = (w >> 1) * 64;

  f32x4 acc[4][4] = {};

  const int sr = tid >> 2;
  const int sk = (tid & 3) * 8;
  const u16* ga = a  + (size_t)(m0 + sr) * GK_ + sk;
  const u16* gb = bw + (size_t)(n0 + sr) * GK_ + sk;

  for (int k0 = 0; k0 < GK_; k0 += 32) {
    uint4 a0 = *(const uint4*)(ga + k0);
    uint4 a1 = *(const uint4*)(ga + (size_t)64 * GK_ + k0);
    uint4 b0 = *(const uint4*)(gb + k0);
    uint4 b1 = *(const uint4*)(gb + (size_t)64 * GK_ + k0);
    __syncthreads();
    *(uint4*)(As + sr * 40 + sk)        = a0;
    *(uint4*)(As + (64 + sr) * 40 + sk) = a1;
    *(uint4*)(Bs + sr * 40 + sk)        = b0;
    *(uint4*)(Bs + (64 + sr) * 40 + sk) = b1;
    __syncthreads();

    bf16x8 af[4], bfr[4];
#pragma unroll
    for (int i = 0; i < 4; ++i) {
      af[i]  = *(const bf16x8*)(As + (qr + i * 16 + col) * 40 + quad * 8);
      bfr[i] = *(const bf16x8*)(Bs + (qc + i * 16 + col) * 40 + quad * 8);
    }
#pragma unroll
    for (int i = 0; i < 4; ++i)
#pragma unroll
      for (int j = 0; j < 4; ++j)
        acc[i][j] = __builtin_amdgcn_mfma_f32_16x16x32_bf16(af[i], bfr[j], acc[i][j], 0, 0, 0);
  }

#pragma unroll
  for (int i = 0; i < 4; ++i)
#pragma unroll
    for (int j = 0; j < 4; ++j)
#pragma unroll
      for (int r = 0; r < 4; ++r)
        c[(size_t)(m0 + qr + i * 16 + quad * 4 + r) * GN_ + n0 + qc + j * 16 + col]
            = acc[i][j][r];
}

// ---------------------------------------------------------------------------
// Fallback vector oproj (per-batch mode only; unchanged).
// ---------------------------------------------------------------------------
__global__ __launch_bounds__(256) void oproj_vec_kernel(
    const u16* __restrict__ o, const void* __restrict__ w,
    float* __restrict__ out, const int* __restrict__ flag)
{
  __shared__ __align__(16) float At[64 * 68];
  __shared__ __align__(16) float Wt[64 * 68];
  const int tid = threadIdx.x;
  const size_t zo = (size_t)blockIdx.z * S_ * V_;
  const int m0 = blockIdx.x * 64;
  const int n0 = blockIdx.y * 64;
  const int tr = tid >> 4, tc = tid & 15;
  const int isf32 = *flag;
  const int srow = tid >> 2, sc = (tid & 3) * 16;

  float acc[4][4] = {};

  for (int k0 = 0; k0 < GK_; k0 += 64) {
    float av[16], wv[16];
    {
      const u16* gp = o + zo + (size_t)(m0 + srow) * GK_ + k0 + sc;
      uint4 u0 = *(const uint4*)gp;
      uint4 u1 = *(const uint4*)(gp + 8);
      av[0]=lo16(u0.x); av[1]=hi16(u0.x); av[2]=lo16(u0.y); av[3]=hi16(u0.y);
      av[4]=lo16(u0.z); av[5]=hi16(u0.z); av[6]=lo16(u0.w); av[7]=hi16(u0.w);
      av[8]=lo16(u1.x); av[9]=hi16(u1.x); av[10]=lo16(u1.y); av[11]=hi16(u1.y);
      av[12]=lo16(u1.z); av[13]=hi16(u1.z); av[14]=lo16(u1.w); av[15]=hi16(u1.w);
    }
    if (isf32) {
      const float4* gp = (const float4*)((const float*)w + (size_t)(n0 + srow) * GK_ + k0 + sc);
#pragma unroll
      for (int i = 0; i < 4; ++i) {
        float4 f = gp[i];
        wv[4*i+0]=f.x; wv[4*i+1]=f.y; wv[4*i+2]=f.z; wv[4*i+3]=f.w;
      }
    } else {
      const u16* gp = (const u16*)w + (size_t)(n0 + srow) * GK_ + k0 + sc;
      uint4 u0 = *(const uint4*)gp;
      uint4 u1 = *(const uint4*)(gp + 8);
      wv[0]=lo16(u0.x); wv[1]=hi16(u0.x); wv[2]=lo16(u0.y); wv[3]=hi16(u0.y);
      wv[4]=lo16(u0.z); wv[5]=hi16(u0.z); wv[6]=lo16(u0.w); wv[7]=hi16(u0.w);
      wv[8]=lo16(u1.x); wv[9]=hi16(u1.x); wv[10]=lo16(u1.y); wv[11]=hi16(u1.y);
      wv[12]=lo16(u1.z); wv[13]=hi16(u1.z); wv[14]=lo16(u1.w); wv[15]=hi16(u1.w);
    }
    __syncthreads();
#pragma unroll
    for (int i = 0; i < 16; ++i) {
      At[(sc + i) * 68 + srow] = av[i];
      Wt[(sc + i) * 68 + srow] = wv[i];
    }
    __syncthreads();

#pragma unroll 4
    for (int kk = 0; kk < 64; ++kk) {
      float4 a4 = *(const float4*)&At[kk * 68 + tr * 4];
      float4 w4 = *(const float4*)&Wt[kk * 68 + tc * 4];
      acc[0][0] += a4.x*w4.x; acc[0][1] += a4.x*w4.y; acc[0][2] += a4.x*w4.z; acc[0][3] += a4.x*w4.w;
      acc[1][0] += a4.y*w4.x; acc[1][1] += a4.y*w4.y; acc[1][2] += a4.y*w4.z; acc[1][3] += a4.y*w4.w;
      acc[2][0] += a4.z*w4.x; acc[2][1] += a4.z*w4.y; acc[2][2] += a4.z*w4.z; acc[2][3] += a4.z*w4.w;
      acc[3][0] += a4.w*w4.x; acc[3][1] += a4.w*w4.y; acc[3][2] += a4.w*w4.z; acc[3][3] += a4.w*w4.w;
    }
  }

#pragma unroll
  for (int r = 0; r < 4; ++r) {
    const int row = m0 + tr * 4 + r;
    *(float4*)(out + zo + (size_t)row * GN_ + n0 + tc * 4) =
        make_float4(acc[r][0], acc[r][1], acc[r][2], acc[r][3]);
  }
}

// ---------------------------------------------------------------------------
extern "C" void kernel_launch(void* const* d_in, const int* in_sizes, int n_in,
                              void* d_out, int out_size, void* d_ws, size_t ws_size,
                              hipStream_t stream) {
  const void* x = d_in[0];
  const void* wqkv = (n_in > 1) ? d_in[1] : d_in[0];
  const void* wout = (n_in > 2) ? d_in[2] : d_in[0];
  for (int i = 0; i < n_in; ++i) {
    if      (in_sizes[i] == B_ * S_ * V_)  x    = d_in[i];
    else if (in_sizes[i] == 3 * HS_ * HS_) wqkv = d_in[i];
    else if (in_sizes[i] == V_ * V_)       wout = d_in[i];
  }
  float* out = (float*)d_out;

  const size_t per_b = (size_t)H_ * S_ * HS_;
  const size_t SV = (size_t)S_ * V_;
  int* flag = (int*)d_ws;
  const bool full = ws_size >= (16 + 16 * per_b * sizeof(u16));
  const size_t stride = full ? 4 * per_b : per_b;
  u16* q = (u16*)((char*)d_ws + 16);
  u16* k = q + stride;
  u16* v = k + stride;
  u16* o = v + stride;

  detect_kernel<<<dim3(1), dim3(256), 0, stream>>>((const unsigned int*)x, flag);
  if (full) {
    qkv_mfma_kernel<<<dim3((B_ * S_ * H_) / 128), dim3(256), 0, stream>>>(
        x, wqkv, q, k, v, flag);
    attn_mfma_kernel<<<dim3(32, 16, B_), dim3(256), 0, stream>>>(q, k, v, o);
    u16* wb = q;   // q dead after attn
    wcvt_kernel<<<dim3((V_ * V_) / 1024), dim3(256), 0, stream>>>(wout, wb, flag);
    oproj_mfma_kernel<<<dim3((B_ * S_) / 128, GN_ / 128), dim3(256), 0, stream>>>(o, wb, out);
  } else {
    for (int b = 0; b < B_; ++b) {
      qkv_kernel<<<dim3(128, 1, 1), dim3(256), 0, stream>>>(x, b, wqkv, q, k, v, flag);
      attn_mfma_kernel<<<dim3(32, 16, 1), dim3(256), 0, stream>>>(q, k, v, o);
      oproj_vec_kernel<<<dim3(32, 16, 1), dim3(256), 0, stream>>>(
          o, wout, out + (size_t)b * SV, flag);
    }
  }
}